// Round 8
// baseline (898.545 us; speedup 1.0000x reference)
//
#include <hip/hip_runtime.h>

// MOGCN on MI355X. Pipeline:
//  k_build_wb : W[3,3,512,256] (+ W@a1, W@a2 cols) -> bf16, k-swizzled [64][2432][8]
//  k_xconv    : X fp32 -> bf16, k-swizzled [64][16384][8]
//  k_bitpack  : adj>0 -> bitset masks (level0), two layouts
//  k_boolmm   : boolean matrix power masks (adj^2>0, adj^3>0) via u64 OR-gather
//  k_gemm_h   : [16384,512]@[512,2432] bf16 MFMA -> h (swizzled) + f1/f2 (fp32)
//  k_rowstats : per-row softmax stats -> C=-m*log2e-log2(l), Z (empty-row handling)
//  k_attgemm  : t-fused masked-softmax @ h, software-pipelined (1 barrier/iter).
//               R7: 32x32x16 MFMA, waves = 2 row-groups(32) x 2 f-halves(128).
//               Same 8-bf16 frags but 32 rows per B-read -> ds_read_b128 count
//               halves (R6 showed kernel is LDS-bound: FETCH 307->50 MB changed
//               nothing). P-gen doubles (each row in 2 f-half waves) - accepted.
//               Geometry kept: 256 thr, grid 768 = 3 blocks/CU, XCD-local mt/48.
//  k_score    : s = tanh(H@Ww+bw)@Wc  (MFMA GEMM)
//  k_combine  : softmax over layers, weighted sum -> out
//
// Workspace map (bytes), total 159,842,304 (~152.4 MiB):
//  [0)            Xs bf16 16,777,216 | Wb bf16 @16,777,216 (2,490,368)  -- dead after k_gemm_h
//  [0)            H32 fp32 50,331,648 (reuses region above; fully written by k_attgemm)
//  [50,331,648)   hsw bf16 75,497,472   [9][16][128][256][8]
//  [125,829,120)  mbA u64 12,582,912    [2 lvl][48][1024][16]
//  [138,412,032)  mbT u64 18,874,368    [9][16][16w][1024i]
//  [157,286,400)  fbuf fp32 1,179,648   [2][9][16384]
//  [158,466,048)  rowC 589,824 | [159,055,872) rowZ 589,824 | [159,645,696) svals 196,608

typedef unsigned long long u64;
typedef __attribute__((ext_vector_type(4))) float f32x4;
typedef __attribute__((ext_vector_type(16))) float f32x16;
typedef __attribute__((ext_vector_type(8))) short bf16x8;

#define NEGF (-9.0e15f)
#define L2E 1.44269504f

__device__ __forceinline__ float fexp2(float x){
#if __has_builtin(__builtin_amdgcn_exp2f)
  return __builtin_amdgcn_exp2f(x);
#else
  return exp2f(x);
#endif
}
__device__ __forceinline__ float flog2(float x){
#if __has_builtin(__builtin_amdgcn_logf)
  return __builtin_amdgcn_logf(x);
#else
  return log2f(x);
#endif
}
__device__ __forceinline__ float frcp(float x){
#if __has_builtin(__builtin_amdgcn_rcpf)
  return __builtin_amdgcn_rcpf(x);
#else
  return 1.0f/x;
#endif
}
__device__ __forceinline__ unsigned short f2bf(float x){   // RNE
  union { float f; unsigned u; } a; a.f = x;
  unsigned r = a.u + 0x7FFFu + ((a.u >> 16) & 1u);
  return (unsigned short)(r >> 16);
}
__device__ __forceinline__ float bf2f(unsigned short h){
  union { unsigned u; float f; } a; a.u = ((unsigned)h) << 16; return a.f;
}
__device__ __forceinline__ unsigned pack_bf16x2(float lo, float hi){ // fast round
  union { float f; unsigned u; } a, b; a.f = lo; b.f = hi;
  unsigned ul = a.u + 0x8000u, uh = b.u + 0x8000u;
#if __has_builtin(__builtin_amdgcn_perm)
  return __builtin_amdgcn_perm(uh, ul, 0x07060302u);
#else
  return (ul >> 16) | (uh & 0xFFFF0000u);
#endif
}
__device__ __forceinline__ float tanh_fast(float x){
  float e = fexp2(x * 2.885390082f);  // exp(2x)
  return 1.0f - 2.0f*frcp(e + 1.0f);
}
__device__ __forceinline__ void async_cp16(void* lds, const void* g){
  __builtin_amdgcn_global_load_lds(
      (const __attribute__((address_space(1))) unsigned int*)g,
      (__attribute__((address_space(3))) unsigned int*)lds, 16, 0, 0);
}

// ---------------- prep kernels ----------------

__global__ void k_build_wb(const float* __restrict__ W, const float* __restrict__ a1,
                           const float* __restrict__ a2, unsigned short* __restrict__ Wb)
{
  int idx = blockIdx.x*256 + threadIdx.x;           // g*2432 + c
  if (idx >= 64*2432) return;
  int c = idx % 2432, g = idx / 2432;
  unsigned short o[8];
  if (c < 2304) {
    int s = c >> 8, f = c & 255, t = s % 3, klq = s / 3;   // s = kl*3 + t
    const float* wp = W + ((size_t)(t*3 + klq)*512)*256 + f;
#pragma unroll
    for (int e = 0; e < 8; ++e) o[e] = f2bf(wp[(size_t)(g*8 + e)*256]);
  } else if (c < 2322) {
    int c2 = c - 2304, s = c2 >> 1, t = s % 3, klq = s / 3;
    const float* av = ((c2 & 1) ? a2 : a1) + (t*3 + klq)*256;
    const float* wp = W + ((size_t)(t*3 + klq)*512)*256;
#pragma unroll
    for (int e = 0; e < 8; ++e) {
      float acc = 0.0f;
      const float* wr = wp + (size_t)(g*8 + e)*256;
      for (int f = 0; f < 256; ++f) acc += wr[f]*av[f];
      o[e] = f2bf(acc);
    }
  } else {
#pragma unroll
    for (int e = 0; e < 8; ++e) o[e] = 0;
  }
  ushort4 lo, hi;
  lo.x=o[0]; lo.y=o[1]; lo.z=o[2]; lo.w=o[3];
  hi.x=o[4]; hi.y=o[5]; hi.z=o[6]; hi.w=o[7];
  ushort4* dst = (ushort4*)(Wb + (size_t)idx*8);
  dst[0] = lo; dst[1] = hi;
}

__global__ void k_xconv(const float* __restrict__ X, unsigned short* __restrict__ Xs)
{
  int idx = blockIdx.x*256 + threadIdx.x;           // g*16384 + bn
  int bn = idx & 16383, g = idx >> 14;
  const float* xp = X + (size_t)bn*512 + g*8;
  ushort4 lo, hi;
  lo.x=f2bf(xp[0]); lo.y=f2bf(xp[1]); lo.z=f2bf(xp[2]); lo.w=f2bf(xp[3]);
  hi.x=f2bf(xp[4]); hi.y=f2bf(xp[5]); hi.z=f2bf(xp[6]); hi.w=f2bf(xp[7]);
  ushort4* dst = (ushort4*)(Xs + (size_t)idx*8);
  dst[0] = lo; dst[1] = hi;
}

__global__ void k_bitpack(const float* __restrict__ adj, u64* __restrict__ mbA0,
                          u64* __restrict__ mbT)
{
  size_t tid = (size_t)blockIdx.x*256 + threadIdx.x;  // adj[b][t][i][j]
  float v = adj[tid];
  u64 msk = __ballot(v > 0.0f);
  if ((threadIdx.x & 63) == 0) {
    size_t word = tid >> 6;
    int w = (int)(word & 15), i = (int)((word >> 4) & 1023);
    int bt = (int)(word >> 14);     // b*3 + t
    int t = bt % 3, b = bt / 3;
    mbA0[((size_t)(t*16 + b)*1024 + i)*16 + w] = msk;
    mbT[(((size_t)t*16 + b)*16 + w)*1024 + i] = msk;   // s = t for level 0
  }
}

__global__ void k_boolmm(const u64* __restrict__ A, const u64* __restrict__ Bm,
                         u64* __restrict__ outA, u64* __restrict__ outT, int sbase)
{
  int tid = blockIdx.x*256 + threadIdx.x;   // 48*1024*16
  int w = tid & 15, i = (tid >> 4) & 1023, tb = tid >> 14;
  const u64* Ar = A + ((size_t)tb*1024 + i)*16;
  const u64* Bb = Bm + (size_t)tb*16384;
  u64 acc = 0;
  for (int ww = 0; ww < 16; ++ww) {
    u64 aw = Ar[ww];
    while (aw) {
      int kk = __builtin_ctzll(aw);
      aw &= aw - 1;
      acc |= Bb[((size_t)(ww*64 + kk))*16 + w];
    }
  }
  if (outA) outA[((size_t)tb*1024 + i)*16 + w] = acc;
  int t = tb >> 4, bq = tb & 15;
  outT[(((size_t)(sbase + t)*16 + bq)*16 + w)*1024 + i] = acc;
}

// ---------------- h = X@W GEMM (bf16 MFMA), fused f1/f2 ----------------

__global__ __launch_bounds__(256) void k_gemm_h(
    const unsigned short* __restrict__ Xs, const unsigned short* __restrict__ Wb,
    unsigned short* __restrict__ hsw, float* __restrict__ fbuf)
{
  __shared__ unsigned short Asl[8*132*8 + 8];
  __shared__ unsigned short Bsl[8*132*8 + 8];
  const int tid = threadIdx.x, lane = tid & 63, wid = tid >> 6;
  int vb = blockIdx.x;                       // XCD swizzle: same mt -> same XCD
  int xc = vb & 7, mrest = vb >> 3;
  int mt = xc + 8*(mrest/19), nt = mrest % 19;
  const int M0 = mt << 7, N0 = nt << 7;
  const int wr = (wid >> 1) << 6, wc = (wid & 1) << 6;
  const int me = lane & 15;
  f32x4 acc[4][4] = {};
  for (int ks64 = 0; ks64 < 8; ++ks64) {
    __syncthreads();
#pragma unroll
    for (int c = 0; c < 4; ++c) {
      int chunk = wid*4 + c, g = chunk >> 1, hh = chunk & 1;
      int ldsoff = (g*132 + hh*64)*8;
      const unsigned short* gpA = Xs + ((size_t)(ks64*8 + g)*16384 + (M0 + hh*64 + lane))*8;
      async_cp16(Asl + ldsoff, gpA);
      const unsigned short* gpB = Wb + ((size_t)(ks64*8 + g)*2432 + (N0 + hh*64 + lane))*8;
      async_cp16(Bsl + ldsoff, gpB);
    }
    __syncthreads();
#pragma unroll
    for (int ks32 = 0; ks32 < 2; ++ks32) {
      const int kg = ks32*4 + (lane >> 4);
      bf16x8 afr[4], bfr[4];
#pragma unroll
      for (int rb = 0; rb < 4; ++rb)
        afr[rb] = *(const bf16x8*)(Asl + (kg*132 + wr + rb*16 + me)*8);
#pragma unroll
      for (int cb = 0; cb < 4; ++cb)
        bfr[cb] = *(const bf16x8*)(Bsl + (kg*132 + wc + cb*16 + me)*8);
#pragma unroll
      for (int rb = 0; rb < 4; ++rb)
#pragma unroll
        for (int cb = 0; cb < 4; ++cb)
          acc[rb][cb] = __builtin_amdgcn_mfma_f32_16x16x32_bf16(afr[rb], bfr[cb], acc[rb][cb], 0, 0, 0);
    }
  }
  const int quad = lane >> 4;
#pragma unroll
  for (int rb = 0; rb < 4; ++rb) {
    int jbase = M0 + wr + rb*16 + quad*4;
    int bidx = jbase >> 10, jn = jbase & 1023;
#pragma unroll
    for (int cb = 0; cb < 4; ++cb) {
      int c = N0 + wc + cb*16 + me;
      f32x4 v = acc[rb][cb];
      if (c < 2304) {
        int s = c >> 8, f = c & 255;
        ushort4 pk;
        pk.x = f2bf(v[0]); pk.y = f2bf(v[1]); pk.z = f2bf(v[2]); pk.w = f2bf(v[3]);
        *(ushort4*)(hsw + (size_t)s*4194304 + (size_t)bidx*262144 + ((jn>>3)*256 + f)*8 + (jn&7)) = pk;
      } else if (c < 2322) {
        int c2 = c - 2304, s = c2 >> 1, wh = c2 & 1;
        *(f32x4*)(fbuf + (size_t)wh*147456 + s*16384 + jbase) = v;
      }
    }
  }
}

// ---------------- per-row softmax stats ----------------

__global__ __launch_bounds__(256) void k_rowstats(
    const u64* __restrict__ mbT, const float* __restrict__ fbuf,
    float* __restrict__ rowC, float* __restrict__ rowZ)
{
  int gw = blockIdx.x*4 + (threadIdx.x >> 6);   // row id: (s*16+b)*1024 + i
  int lane = threadIdx.x & 63;
  int i = gw & 1023, sb = gw >> 10;
  int b = sb & 15, s = sb >> 4;
  const u64* mrow = mbT + (size_t)sb*16384 + i;
  const float* f1g = fbuf + s*16384 + b*1024;
  const float* f2g = fbuf + 147456 + s*16384 + b*1024;
  float f1i = f1g[i];
  float vals[16];
  float mmax = NEGF;
#pragma unroll
  for (int w = 0; w < 16; ++w) {
    u64 word = mrow[(size_t)w*1024];
    float f2v = f2g[w*64 + lane];
    float sv = f1i + f2v;
    float lk = fmaxf(sv, 0.2f*sv);
    float val = ((word >> lane) & 1ull) ? lk : NEGF;
    vals[w] = val;
    mmax = fmaxf(mmax, val);
  }
#pragma unroll
  for (int off = 32; off; off >>= 1) mmax = fmaxf(mmax, __shfl_xor(mmax, off));
  float l = 0.0f;
#pragma unroll
  for (int w = 0; w < 16; ++w) l += fexp2((vals[w] - mmax)*L2E);
#pragma unroll
  for (int off = 32; off; off >>= 1) l += __shfl_xor(l, off);
  if (lane == 0) {
    bool empty = (mmax < -8.0e15f);
    rowC[gw] = (empty ? 0.0f : -mmax*L2E) - flog2(l);
    rowZ[gw] = empty ? 0.0f : NEGF;
  }
}

// ---------------- fused attention GEMM: H = sum_t softmax(mask_t(e_t)) @ h_t --------
// R7: 32x32x16 MFMA. Grid [mt 0..15 SLOW][g=kl*16+b 0..47] -> 768 blocks (3/CU,
// same-group blocks share vb%8 -> same XCD). 256 threads = 4 waves:
// wave = (rg = wid>>1: 32-row group) x (fh = wid&1: 128-f half). acc = 4 x f32x16.
// Per 32-j iter: 2 k-steps x 4 col-blocks = 8 MFMA, 8 ds_read_b128 (halved vs R6).
// A-frag: lane holds row=lane&31, k-octet=lane>>5 (8 consecutive j).
// C/D: col=lane&31, row=(reg&3)+8*(reg>>2)+4*(lane>>5)  [m74/m101 verified].

__global__ __launch_bounds__(256, 3) void k_attgemm(
    const unsigned short* __restrict__ hsw, const float* __restrict__ fbuf,
    const float* __restrict__ rowC, const float* __restrict__ rowZ,
    const u64* __restrict__ mbT, float* __restrict__ H32)
{
  __shared__ unsigned short Bts[2*4*260*8];   // 2 half-buffers, 16640B each
  const int tid = threadIdx.x, lane = tid & 63, wid = tid >> 6;
  const int n32 = lane & 31, ko = lane >> 5;
  const int rg = wid >> 1, fh = wid & 1;
  int vb = blockIdx.x;
  int mt = vb / 48, g = vb % 48;              // g%8 constant across a group's 16 blocks
  int kl = g >> 4, b = g & 15;
  const int i0w = mt*64 + rg*32;
  const int ir0 = i0w + n32;                  // this lane's row (A/mask/f1/C/Z)
  const int f0 = fh*128;
  const unsigned short* hbase = hsw + (size_t)(kl*3)*4194304 + (size_t)b*262144;
  const float* fb1 = fbuf + (kl*3)*16384 + b*1024;
  const float* fb2 = fbuf + 147456 + (kl*3)*16384 + b*1024;
  const float* Cb = rowC + ((kl*3)*16 + b)*1024;
  const float* Zb = rowZ + ((kl*3)*16 + b)*1024;
  const u64* mb = mbT + (size_t)((kl*3)*16 + b)*16384;   // t-stride 262144 u64

  float f1v, Cv, Zv;
  f32x16 acc[4] = {};

  // seed: stage iter 0 (t=0, st=0, ks=0) into buffer 0
  {
    const unsigned short* hstage = hbase + wid*2048;
    unsigned short* lb = Bts + wid*2080;
#pragma unroll
    for (int c = 0; c < 4; ++c)
      async_cp16(lb + c*512, hstage + c*512 + lane*8);
  }
  u64 mw = mb[ir0];
  u64 nm = 0;

  for (int it = 0; it < 96; ++it) {
    const int tt = it >> 5, kk = it & 1;
    const int st = (it >> 1) & 15;
    if ((it & 31) == 0) {                 // t boundary: per-row constants for this t
      f1v = fb1[tt*16384 + ir0];
      Cv  = Cb[tt*16384 + ir0];
      Zv  = Zb[tt*16384 + ir0];
    }
    if (!kk && it) mw = nm;               // adopt prefetched mask

    __syncthreads();   // drains vmcnt: current half's loads issued one compute ago

    if (it + 1 < 96) {                    // stage next half into other buffer
      int nx = it + 1;
      int nt2 = nx >> 5, ns = (nx >> 1) & 15, nk = nx & 1;
      const unsigned short* hstage = hbase + (size_t)nt2*4194304 + ns*16384 + (nk*4 + wid)*2048;
      unsigned short* lb = Bts + nk*8320 + wid*2080;
#pragma unroll
      for (int c = 0; c < 4; ++c)
        async_cp16(lb + c*512, hstage + c*512 + lane*8);
    }
    if (kk && it + 1 < 96) {              // prefetch mask for next (t,st)
      int gid = (it + 1) >> 1;
      int nt2 = gid >> 4, ns = gid & 15;
      nm = mb[(size_t)nt2*262144 + ns*1024 + ir0];
    }

#pragma unroll
    for (int ks = 0; ks < 2; ++ks) {      // two 16-j k-steps per 32-j half
      const int jb = kk*32 + ks*16 + ko*8;   // lane's j-octet base within st-block
      // f2 for this lane's octet (half-wave-uniform addresses -> L1 broadcast)
      const float* f2p = fb2 + tt*16384 + st*64 + jb;
      float4 fa = *(const float4*)(f2p);
      float4 fb4 = *(const float4*)(f2p + 4);
      float f2e[8] = {fa.x, fa.y, fa.z, fa.w, fb4.x, fb4.y, fb4.z, fb4.w};
      unsigned mby = (unsigned)((mw >> jb) & 0xFFull);
      union { bf16x8 v; unsigned u[4]; } ua;
#pragma unroll
      for (int p = 0; p < 4; ++p) {
        float s0 = f1v + f2e[2*p];
        float l0 = fmaxf(s0, 0.2f*s0);
        float v0 = (mby & (1u << (2*p))) ? l0 : Zv;
        float p0 = fexp2(__builtin_fmaf(v0, L2E, Cv));
        float s1 = f1v + f2e[2*p+1];
        float l1 = fmaxf(s1, 0.2f*s1);
        float v1 = (mby & (2u << (2*p))) ? l1 : Zv;
        float p1 = fexp2(__builtin_fmaf(v1, L2E, Cv));
        ua.u[p] = pack_bf16x2(p0, p1);
      }
      // B frags: octet index = ks*2 + ko within the kk half-buffer
      const unsigned short* bbase = Bts + kk*8320 + (ks*2 + ko)*2080;
#pragma unroll
      for (int cb = 0; cb < 4; ++cb) {
        bf16x8 bf = *(const bf16x8*)(bbase + (f0 + cb*32 + n32)*8);
        acc[cb] = __builtin_amdgcn_mfma_f32_32x32x16_bf16(ua.v, bf, acc[cb], 0, 0, 0);
      }
    }
  }

  // epilogue: plain stores; C/D row = (reg&3)+8*(reg>>2)+4*ko, col = n32
#pragma unroll
  for (int cb = 0; cb < 4; ++cb) {
    int f = f0 + cb*32 + n32;
    float* hp0 = H32 + (((size_t)b*1024 + i0w + 4*ko)*3 + kl)*256 + f;
#pragma unroll
    for (int reg = 0; reg < 16; ++reg) {
      int row = (reg & 3) + 8*(reg >> 2);
      hp0[(size_t)row*768] = acc[cb][reg];
    }
  }
}

// ---------------- layer attention: s = tanh(H@Ww+bw)@Wc (MFMA) ----------------

__global__ __launch_bounds__(256) void k_score(
    const float* __restrict__ H32, const float* __restrict__ Ww,
    const float* __restrict__ bwv, const float* __restrict__ Wcv, float* __restrict__ svals)
{
  __shared__ unsigned short Bs[8*7*64*8];   // 57344 B
  __shared__ float bwL[128], WcL[128];
  const int tid = threadIdx.x, lane = tid & 63, wid = tid >> 6;
  const int me = lane & 15, quad = lane >> 4;
  for (int idx = tid; idx < 3584; idx += 256) {
    int kk = idx / 448, rem = idx % 448;
    int cb = rem >> 6, l = rem & 63;
    int n = cb*16 + (l & 15);
    int kbase = kk*32 + (l >> 4)*8;
    ushort4 lo, hi;
    if (n < 100) {
      const float* wp = Ww + (size_t)kbase*100 + n;
      lo.x = f2bf(wp[0]);   lo.y = f2bf(wp[100]); lo.z = f2bf(wp[200]); lo.w = f2bf(wp[300]);
      hi.x = f2bf(wp[400]); hi.y = f2bf(wp[500]); hi.z = f2bf(wp[600]); hi.w = f2bf(wp[700]);
    } else {
      lo.x=lo.y=lo.z=lo.w=0; hi.x=hi.y=hi.z=hi.w=0;
    }
    ushort4* dst = (ushort4*)(Bs + (size_t)idx*8);
    dst[0] = lo; dst[1] = hi;
  }
  if (tid < 128) {
    bwL[tid] = (tid < 100) ? bwv[tid] : 0.0f;
    WcL[tid] = (tid < 100) ? Wcv[tid] : 0.0f;
  }
  __syncthreads();

  const int row0 = blockIdx.x*64 + wid*16;
  const float* Arow = H32 + (size_t)(row0 + me)*256;
  f32x4 acc[7] = {};
#pragma unroll
  for (int kk = 0; kk < 8; ++kk) {
    const float* ap = Arow + kk*32 + quad*8;
    float4 a0 = *(const float4*)(ap);
    float4 a1 = *(const float4*)(ap + 4);
    union { bf16x8 v; unsigned u[4]; } ua;
    ua.u[0] = pack_bf16x2(a0.x, a0.y);
    ua.u[1] = pack_bf16x2(a0.z, a0.w);
    ua.u[2] = pack_bf16x2(a1.x, a1.y);
    ua.u[3] = pack_bf16x2(a1.z, a1.w);
#pragma unroll
    for (int cb = 0; cb < 7; ++cb) {
      bf16x8 bf = *(const bf16x8*)(Bs + ((size_t)(kk*7 + cb)*64 + lane)*8);
      acc[cb] = __builtin_amdgcn_mfma_f32_16x16x32_bf16(ua.v, bf, acc[cb], 0, 0, 0);
    }
  }
#pragma unroll
  for (int r = 0; r < 4; ++r) {
    float contrib = 0.0f;
#pragma unroll
    for (int cb = 0; cb < 7; ++cb) {
      int col = cb*16 + me;
      contrib += tanh_fast(acc[cb][r] + bwL[col]) * WcL[col];
    }
    contrib += __shfl_xor(contrib, 1);
    contrib += __shfl_xor(contrib, 2);
    contrib += __shfl_xor(contrib, 4);
    contrib += __shfl_xor(contrib, 8);
    if (me == 0) svals[row0 + quad*4 + r] = contrib;
  }
}

__global__ void k_combine(const float* __restrict__ svals, const float* __restrict__ H32,
                          float* __restrict__ out)
{
  int tid = blockIdx.x*256 + threadIdx.x;
  int fq = tid & 63, bn = tid >> 6;
  float s0 = svals[bn*3], s1 = svals[bn*3+1], s2 = svals[bn*3+2];
  float mm = fmaxf(s0, fmaxf(s1, s2));
  float e0 = fexp2((s0-mm)*L2E), e1 = fexp2((s1-mm)*L2E), e2 = fexp2((s2-mm)*L2E);
  float inv = frcp(e0 + e1 + e2);
  const f32x4* h0 = (const f32x4*)(H32 + (size_t)bn*768) + fq;
  const f32x4* h1 = (const f32x4*)(H32 + (size_t)bn*768 + 256) + fq;
  const f32x4* h2 = (const f32x4*)(H32 + (size_t)bn*768 + 512) + fq;
  f32x4 r = (e0*(*h0) + e1*(*h1) + e2*(*h2))*inv;
  *((f32x4*)out + (size_t)bn*64 + fq) = r;
}

// ---------------- launcher ----------------

extern "C" void kernel_launch(void* const* d_in, const int* in_sizes, int n_in,
                              void* d_out, int out_size, void* d_ws, size_t ws_size,
                              hipStream_t stream) {
  const float* adj = (const float*)d_in[0];
  const float* X   = (const float*)d_in[1];
  const float* W   = (const float*)d_in[2];
  const float* a1  = (const float*)d_in[3];
  const float* a2  = (const float*)d_in[4];
  const float* Ww  = (const float*)d_in[5];
  const float* bw  = (const float*)d_in[6];
  const float* Wc  = (const float*)d_in[7];
  float* out = (float*)d_out;
  char* ws = (char*)d_ws;

  unsigned short* Xs  = (unsigned short*)(ws + 0);
  unsigned short* Wb  = (unsigned short*)(ws + 16777216);
  float* H32          = (float*)(ws + 0);                // reuses Xs/Wb region
  unsigned short* hsw = (unsigned short*)(ws + 50331648);
  u64* mbA            = (u64*)(ws + 125829120);
  u64* mbT            = (u64*)(ws + 138412032);
  float* fbuf         = (float*)(ws + 157286400);
  float* rowC         = (float*)(ws + 158466048);
  float* rowZ         = (float*)(ws + 159055872);
  float* svals        = (float*)(ws + 159645696);

  k_build_wb<<<608, 256, 0, stream>>>(W, a1, a2, Wb);
  k_xconv<<<4096, 256, 0, stream>>>(X, Xs);
  k_bitpack<<<196608, 256, 0, stream>>>(adj, mbA, mbT);
  k_boolmm<<<3072, 256, 0, stream>>>(mbA, mbA, mbA + 786432, mbT, 3);
  k_boolmm<<<3072, 256, 0, stream>>>(mbA + 786432, mbA, (u64*)nullptr, mbT, 6);
  k_gemm_h<<<2432, 256, 0, stream>>>(Xs, Wb, hsw, fbuf);
  k_rowstats<<<36864, 256, 0, stream>>>(mbT, fbuf, rowC, rowZ);
  k_attgemm<<<768, 256, 0, stream>>>(hsw, fbuf, rowC, rowZ, mbT, H32);
  k_score<<<768, 256, 0, stream>>>(H32, Ww, bw, Wc, svals);
  k_combine<<<4096, 256, 0, stream>>>(svals, H32, out);
}

// Round 9
// 844.137 us; speedup vs baseline: 1.0645x; 1.0645x over previous
//
#include <hip/hip_runtime.h>

// MOGCN on MI355X. Pipeline:
//  k_build_wb : W[3,3,512,256] (+ W@a1, W@a2 cols) -> bf16, k-swizzled [64][2432][8]
//  k_xconv    : X fp32 -> bf16, k-swizzled [64][16384][8]
//  k_bitpack  : adj>0 -> bitset masks (level0), two layouts
//  k_boolmm   : boolean matrix power masks (adj^2>0, adj^3>0) via u64 OR-gather
//  k_gemm_h   : [16384,512]@[512,2432] bf16 MFMA -> h (swizzled) + f1L/f2L (=f·log2e)
//  k_rowstats : log2-domain softmax stats -> per-row A=f1L+C, B=0.8C, Z2
//  k_attgemm  : R8 = R6 structure (16x16x32, 4 waves x 16 rows, acc[16], grid 768
//               mt-slow XCD-local; measured 135us) + 5-op log2-domain P-gen:
//               u=f2L+A; w=fma(u,.2,B); v=max(u,w); sel=mask?v:Z2; p=exp2(sel).
//               R7 (32x32, conflicts=0, halved reads) proved LDS was NOT the
//               bottleneck - P-gen VALU is (~45us per duplication). Ops/value
//               is the only remaining lever.
//  k_score    : s = tanh(H@Ww+bw)@Wc  (MFMA GEMM)
//  k_combine  : softmax over layers, weighted sum -> out
//
// Workspace map (bytes), total 159,842,304 (~152.4 MiB):
//  [0)            Xs bf16 16,777,216 | Wb bf16 @16,777,216 (2,490,368)  -- dead after k_gemm_h
//  [0)            H32 fp32 50,331,648 (reuses region above; fully written by k_attgemm)
//  [50,331,648)   hsw bf16 75,497,472   [9][16][128][256][8]
//  [125,829,120)  mbA u64 12,582,912; lvl0 dead after boolmm-1 -> rowA/rowB/rowZ2
//                 (3 x 589,824 B at +0/+589,824/+1,179,648; lvl1 at +6,291,456 safe)
//  [138,412,032)  mbT u64 18,874,368    [9][16][16w][1024i]
//  [157,286,400)  fbuf fp32 1,179,648   [2][9][16384]  (values pre-scaled by log2e)
//  [158,466,048)  (rowC/rowZ slots unused since R8) | [159,645,696) svals 196,608

typedef unsigned long long u64;
typedef __attribute__((ext_vector_type(4))) float f32x4;
typedef __attribute__((ext_vector_type(8))) short bf16x8;

#define NEGF (-9.0e15f)
#define L2E 1.44269504f

__device__ __forceinline__ float fexp2(float x){
#if __has_builtin(__builtin_amdgcn_exp2f)
  return __builtin_amdgcn_exp2f(x);
#else
  return exp2f(x);
#endif
}
__device__ __forceinline__ float flog2(float x){
#if __has_builtin(__builtin_amdgcn_logf)
  return __builtin_amdgcn_logf(x);
#else
  return log2f(x);
#endif
}
__device__ __forceinline__ float frcp(float x){
#if __has_builtin(__builtin_amdgcn_rcpf)
  return __builtin_amdgcn_rcpf(x);
#else
  return 1.0f/x;
#endif
}
__device__ __forceinline__ unsigned short f2bf(float x){   // RNE
  union { float f; unsigned u; } a; a.f = x;
  unsigned r = a.u + 0x7FFFu + ((a.u >> 16) & 1u);
  return (unsigned short)(r >> 16);
}
__device__ __forceinline__ float bf2f(unsigned short h){
  union { unsigned u; float f; } a; a.u = ((unsigned)h) << 16; return a.f;
}
__device__ __forceinline__ unsigned pack_bf16x2(float lo, float hi){ // fast round
  union { float f; unsigned u; } a, b; a.f = lo; b.f = hi;
  unsigned ul = a.u + 0x8000u, uh = b.u + 0x8000u;
#if __has_builtin(__builtin_amdgcn_perm)
  return __builtin_amdgcn_perm(uh, ul, 0x07060302u);
#else
  return (ul >> 16) | (uh & 0xFFFF0000u);
#endif
}
__device__ __forceinline__ float tanh_fast(float x){
  float e = fexp2(x * 2.885390082f);  // exp(2x)
  return 1.0f - 2.0f*frcp(e + 1.0f);
}
__device__ __forceinline__ void async_cp16(void* lds, const void* g){
  __builtin_amdgcn_global_load_lds(
      (const __attribute__((address_space(1))) unsigned int*)g,
      (__attribute__((address_space(3))) unsigned int*)lds, 16, 0, 0);
}

// ---------------- prep kernels ----------------

__global__ void k_build_wb(const float* __restrict__ W, const float* __restrict__ a1,
                           const float* __restrict__ a2, unsigned short* __restrict__ Wb)
{
  int idx = blockIdx.x*256 + threadIdx.x;           // g*2432 + c
  if (idx >= 64*2432) return;
  int c = idx % 2432, g = idx / 2432;
  unsigned short o[8];
  if (c < 2304) {
    int s = c >> 8, f = c & 255, t = s % 3, klq = s / 3;   // s = kl*3 + t
    const float* wp = W + ((size_t)(t*3 + klq)*512)*256 + f;
#pragma unroll
    for (int e = 0; e < 8; ++e) o[e] = f2bf(wp[(size_t)(g*8 + e)*256]);
  } else if (c < 2322) {
    int c2 = c - 2304, s = c2 >> 1, t = s % 3, klq = s / 3;
    const float* av = ((c2 & 1) ? a2 : a1) + (t*3 + klq)*256;
    const float* wp = W + ((size_t)(t*3 + klq)*512)*256;
#pragma unroll
    for (int e = 0; e < 8; ++e) {
      float acc = 0.0f;
      const float* wr = wp + (size_t)(g*8 + e)*256;
      for (int f = 0; f < 256; ++f) acc += wr[f]*av[f];
      o[e] = f2bf(acc);
    }
  } else {
#pragma unroll
    for (int e = 0; e < 8; ++e) o[e] = 0;
  }
  ushort4 lo, hi;
  lo.x=o[0]; lo.y=o[1]; lo.z=o[2]; lo.w=o[3];
  hi.x=o[4]; hi.y=o[5]; hi.z=o[6]; hi.w=o[7];
  ushort4* dst = (ushort4*)(Wb + (size_t)idx*8);
  dst[0] = lo; dst[1] = hi;
}

__global__ void k_xconv(const float* __restrict__ X, unsigned short* __restrict__ Xs)
{
  int idx = blockIdx.x*256 + threadIdx.x;           // g*16384 + bn
  int bn = idx & 16383, g = idx >> 14;
  const float* xp = X + (size_t)bn*512 + g*8;
  ushort4 lo, hi;
  lo.x=f2bf(xp[0]); lo.y=f2bf(xp[1]); lo.z=f2bf(xp[2]); lo.w=f2bf(xp[3]);
  hi.x=f2bf(xp[4]); hi.y=f2bf(xp[5]); hi.z=f2bf(xp[6]); hi.w=f2bf(xp[7]);
  ushort4* dst = (ushort4*)(Xs + (size_t)idx*8);
  dst[0] = lo; dst[1] = hi;
}

__global__ void k_bitpack(const float* __restrict__ adj, u64* __restrict__ mbA0,
                          u64* __restrict__ mbT)
{
  size_t tid = (size_t)blockIdx.x*256 + threadIdx.x;  // adj[b][t][i][j]
  float v = adj[tid];
  u64 msk = __ballot(v > 0.0f);
  if ((threadIdx.x & 63) == 0) {
    size_t word = tid >> 6;
    int w = (int)(word & 15), i = (int)((word >> 4) & 1023);
    int bt = (int)(word >> 14);     // b*3 + t
    int t = bt % 3, b = bt / 3;
    mbA0[((size_t)(t*16 + b)*1024 + i)*16 + w] = msk;
    mbT[(((size_t)t*16 + b)*16 + w)*1024 + i] = msk;   // s = t for level 0
  }
}

__global__ void k_boolmm(const u64* __restrict__ A, const u64* __restrict__ Bm,
                         u64* __restrict__ outA, u64* __restrict__ outT, int sbase)
{
  int tid = blockIdx.x*256 + threadIdx.x;   // 48*1024*16
  int w = tid & 15, i = (tid >> 4) & 1023, tb = tid >> 14;
  const u64* Ar = A + ((size_t)tb*1024 + i)*16;
  const u64* Bb = Bm + (size_t)tb*16384;
  u64 acc = 0;
  for (int ww = 0; ww < 16; ++ww) {
    u64 aw = Ar[ww];
    while (aw) {
      int kk = __builtin_ctzll(aw);
      aw &= aw - 1;
      acc |= Bb[((size_t)(ww*64 + kk))*16 + w];
    }
  }
  if (outA) outA[((size_t)tb*1024 + i)*16 + w] = acc;
  int t = tb >> 4, bq = tb & 15;
  outT[(((size_t)(sbase + t)*16 + bq)*16 + w)*1024 + i] = acc;
}

// ---------------- h = X@W GEMM (bf16 MFMA), fused f1L/f2L (pre-scaled log2e) -------

__global__ __launch_bounds__(256) void k_gemm_h(
    const unsigned short* __restrict__ Xs, const unsigned short* __restrict__ Wb,
    unsigned short* __restrict__ hsw, float* __restrict__ fbuf)
{
  __shared__ unsigned short Asl[8*132*8 + 8];
  __shared__ unsigned short Bsl[8*132*8 + 8];
  const int tid = threadIdx.x, lane = tid & 63, wid = tid >> 6;
  int vb = blockIdx.x;                       // XCD swizzle: same mt -> same XCD
  int xc = vb & 7, mrest = vb >> 3;
  int mt = xc + 8*(mrest/19), nt = mrest % 19;
  const int M0 = mt << 7, N0 = nt << 7;
  const int wr = (wid >> 1) << 6, wc = (wid & 1) << 6;
  const int me = lane & 15;
  f32x4 acc[4][4] = {};
  for (int ks64 = 0; ks64 < 8; ++ks64) {
    __syncthreads();
#pragma unroll
    for (int c = 0; c < 4; ++c) {
      int chunk = wid*4 + c, g = chunk >> 1, hh = chunk & 1;
      int ldsoff = (g*132 + hh*64)*8;
      const unsigned short* gpA = Xs + ((size_t)(ks64*8 + g)*16384 + (M0 + hh*64 + lane))*8;
      async_cp16(Asl + ldsoff, gpA);
      const unsigned short* gpB = Wb + ((size_t)(ks64*8 + g)*2432 + (N0 + hh*64 + lane))*8;
      async_cp16(Bsl + ldsoff, gpB);
    }
    __syncthreads();
#pragma unroll
    for (int ks32 = 0; ks32 < 2; ++ks32) {
      const int kg = ks32*4 + (lane >> 4);
      bf16x8 afr[4], bfr[4];
#pragma unroll
      for (int rb = 0; rb < 4; ++rb)
        afr[rb] = *(const bf16x8*)(Asl + (kg*132 + wr + rb*16 + me)*8);
#pragma unroll
      for (int cb = 0; cb < 4; ++cb)
        bfr[cb] = *(const bf16x8*)(Bsl + (kg*132 + wc + cb*16 + me)*8);
#pragma unroll
      for (int rb = 0; rb < 4; ++rb)
#pragma unroll
        for (int cb = 0; cb < 4; ++cb)
          acc[rb][cb] = __builtin_amdgcn_mfma_f32_16x16x32_bf16(afr[rb], bfr[cb], acc[rb][cb], 0, 0, 0);
    }
  }
  const int quad = lane >> 4;
#pragma unroll
  for (int rb = 0; rb < 4; ++rb) {
    int jbase = M0 + wr + rb*16 + quad*4;
    int bidx = jbase >> 10, jn = jbase & 1023;
#pragma unroll
    for (int cb = 0; cb < 4; ++cb) {
      int c = N0 + wc + cb*16 + me;
      f32x4 v = acc[rb][cb];
      if (c < 2304) {
        int s = c >> 8, f = c & 255;
        ushort4 pk;
        pk.x = f2bf(v[0]); pk.y = f2bf(v[1]); pk.z = f2bf(v[2]); pk.w = f2bf(v[3]);
        *(ushort4*)(hsw + (size_t)s*4194304 + (size_t)bidx*262144 + ((jn>>3)*256 + f)*8 + (jn&7)) = pk;
      } else if (c < 2322) {
        int c2 = c - 2304, s = c2 >> 1, wh = c2 & 1;
        *(f32x4*)(fbuf + (size_t)wh*147456 + s*16384 + jbase) = v * L2E;  // log2 domain
      }
    }
  }
}

// ---------------- per-row softmax stats (log2 domain) ----------------
// fbuf holds f1L=f1*log2e, f2L=f2*log2e. Emits per row:
//   A = f1L + C,  B = 0.8*C,  Z2 = empty ? C : -inf   where C = -m' - log2(l)
// P in attgemm: p = exp2( mask ? max(u, 0.2u + B) : Z2 ),  u = f2L + A.

__global__ __launch_bounds__(256) void k_rowstats(
    const u64* __restrict__ mbT, const float* __restrict__ fbuf,
    float* __restrict__ rowA, float* __restrict__ rowB, float* __restrict__ rowZ2)
{
  int gw = blockIdx.x*4 + (threadIdx.x >> 6);   // row id: (s*16+b)*1024 + i
  int lane = threadIdx.x & 63;
  int i = gw & 1023, sb = gw >> 10;
  int b = sb & 15, s = sb >> 4;
  const u64* mrow = mbT + (size_t)sb*16384 + i;
  const float* f1g = fbuf + s*16384 + b*1024;
  const float* f2g = fbuf + 147456 + s*16384 + b*1024;
  float f1i = f1g[i];
  float vals[16];
  float mmax = NEGF;
#pragma unroll
  for (int w = 0; w < 16; ++w) {
    u64 word = mrow[(size_t)w*1024];
    float u0 = f1i + f2g[w*64 + lane];          // (f1+f2)*log2e
    float lk = fmaxf(u0, 0.2f*u0);              // leaky in log2 domain
    float val = ((word >> lane) & 1ull) ? lk : NEGF;
    vals[w] = val;
    mmax = fmaxf(mmax, val);
  }
#pragma unroll
  for (int off = 32; off; off >>= 1) mmax = fmaxf(mmax, __shfl_xor(mmax, off));
  float l = 0.0f;
#pragma unroll
  for (int w = 0; w < 16; ++w) l += fexp2(vals[w] - mmax);
#pragma unroll
  for (int off = 32; off; off >>= 1) l += __shfl_xor(l, off);
  if (lane == 0) {
    bool empty = (mmax < -8.0e15f);
    float C = (empty ? 0.0f : -mmax) - flog2(l);
    rowA[gw]  = f1i + C;
    rowB[gw]  = 0.8f*C;
    rowZ2[gw] = empty ? C : NEGF;
  }
}

// ---------------- fused attention GEMM: H = sum_t softmax(mask_t(e_t)) @ h_t --------
// R8 = R6 structure: grid [mt 0..15 SLOW][g=kl*16+b 0..47] -> 768 blocks (3/CU;
// same-group blocks share vb%8 -> same XCD). 256 threads = 4 waves x 16 rows,
// acc[16]. 96 iterations over (t, st, ks-half); one barrier per iteration; staging
// for iter i+1 issued right after it. Plain stores. P-gen: 5 ops/value.

__global__ __launch_bounds__(256, 3) void k_attgemm(
    const unsigned short* __restrict__ hsw, const float* __restrict__ fbuf,
    const float* __restrict__ rowA, const float* __restrict__ rowB,
    const float* __restrict__ rowZ2,
    const u64* __restrict__ mbT, float* __restrict__ H32)
{
  __shared__ unsigned short Bts[2*4*260*8];   // 2 half-buffers, 16640B each
  const int tid = threadIdx.x, lane = tid & 63, wid = tid >> 6;
  const int me = lane & 15, quad = lane >> 4;
  int vb = blockIdx.x;
  int mt = vb / 48, g = vb % 48;              // g%8 constant across a group's 16 blocks
  int kl = g >> 4, b = g & 15;
  const int i0w = mt*64 + wid*16;
  const int ir0 = i0w + me;
  const unsigned short* hbase = hsw + (size_t)(kl*3)*4194304 + (size_t)b*262144;
  const float* fb2 = fbuf + 147456 + (kl*3)*16384 + b*1024;   // f2L
  const float* Ab = rowA + ((kl*3)*16 + b)*1024;
  const float* Bb = rowB + ((kl*3)*16 + b)*1024;
  const float* Zb = rowZ2 + ((kl*3)*16 + b)*1024;
  const u64* mb = mbT + (size_t)((kl*3)*16 + b)*16384;   // t-stride 262144 u64

  float Av, Bv, Zv;
  f32x4 acc[16] = {};

  // seed: stage iter 0 (t=0, st=0, ks=0) into buffer 0
  {
    const unsigned short* hstage = hbase + wid*2048;
    unsigned short* lb = Bts + wid*2080;
#pragma unroll
    for (int c = 0; c < 4; ++c)
      async_cp16(lb + c*512, hstage + c*512 + lane*8);
  }
  u64 mw = mb[ir0];
  u64 nm = 0;

  for (int it = 0; it < 96; ++it) {
    const int tt = it >> 5, kk = it & 1;
    const int st = (it >> 1) & 15;
    if ((it & 31) == 0) {                 // t boundary: per-row constants for this t
      Av = Ab[tt*16384 + ir0];
      Bv = Bb[tt*16384 + ir0];
      Zv = Zb[tt*16384 + ir0];
    }
    if (!kk && it) mw = nm;               // adopt prefetched mask

    __syncthreads();   // drains vmcnt: current half's loads issued one compute ago

    if (it + 1 < 96) {                    // stage next half into other buffer
      int nx = it + 1;
      int nt2 = nx >> 5, ns = (nx >> 1) & 15, nk = nx & 1;
      const unsigned short* hstage = hbase + (size_t)nt2*4194304 + ns*16384 + (nk*4 + wid)*2048;
      unsigned short* lb = Bts + nk*8320 + wid*2080;
#pragma unroll
      for (int c = 0; c < 4; ++c)
        async_cp16(lb + c*512, hstage + c*512 + lane*8);
    }
    if (kk && it + 1 < 96) {              // prefetch mask for next (t,st)
      int gid = (it + 1) >> 1;
      int nt2 = gid >> 4, ns = gid & 15;
      nm = mb[(size_t)nt2*262144 + ns*1024 + ir0];
    }

    // f2L for this 32-k chunk (uniform-per-quad addresses -> L1 broadcast)
    const float* f2p = fb2 + tt*16384 + st*64 + kk*32 + quad*8;
    float4 fa = *(const float4*)(f2p);
    float4 fb4 = *(const float4*)(f2p + 4);
    float f2e[8] = {fa.x, fa.y, fa.z, fa.w, fb4.x, fb4.y, fb4.z, fb4.w};

    const int kloc = kk*32 + quad*8;
    unsigned mby = (unsigned)((mw >> kloc) & 0xFFull);
    union { bf16x8 v; unsigned u[4]; } ua;
#pragma unroll
    for (int p = 0; p < 4; ++p) {
      float u0 = f2e[2*p] + Av;
      float w0 = fmaxf(u0, __builtin_fmaf(u0, 0.2f, Bv));
      float p0 = fexp2((mby & (1u << (2*p))) ? w0 : Zv);
      float u1 = f2e[2*p+1] + Av;
      float w1 = fmaxf(u1, __builtin_fmaf(u1, 0.2f, Bv));
      float p1 = fexp2((mby & (2u << (2*p))) ? w1 : Zv);
      ua.u[p] = pack_bf16x2(p0, p1);
    }
    const unsigned short* bbase = Bts + kk*8320 + quad*2080;
#pragma unroll
    for (int cb = 0; cb < 16; ++cb) {
      bf16x8 bf = *(const bf16x8*)(bbase + (cb*16 + me)*8);
      acc[cb] = __builtin_amdgcn_mfma_f32_16x16x32_bf16(ua.v, bf, acc[cb], 0, 0, 0);
    }
  }

  // epilogue: plain stores (each (kl,b,row,f) written exactly once)
  {
    int io = i0w + quad*4;
#pragma unroll
    for (int cb = 0; cb < 16; ++cb) {
      int f = cb*16 + me;
      float* hp = H32 + (((size_t)b*1024 + io)*3 + kl)*256 + f;
#pragma unroll
      for (int r = 0; r < 4; ++r)
        hp[(size_t)r*768] = acc[cb][r];
    }
  }
}

// ---------------- layer attention: s = tanh(H@Ww+bw)@Wc (MFMA) ----------------

__global__ __launch_bounds__(256) void k_score(
    const float* __restrict__ H32, const float* __restrict__ Ww,
    const float* __restrict__ bwv, const float* __restrict__ Wcv, float* __restrict__ svals)
{
  __shared__ unsigned short Bs[8*7*64*8];   // 57344 B
  __shared__ float bwL[128], WcL[128];
  const int tid = threadIdx.x, lane = tid & 63, wid = tid >> 6;
  const int me = lane & 15, quad = lane >> 4;
  for (int idx = tid; idx < 3584; idx += 256) {
    int kk = idx / 448, rem = idx % 448;
    int cb = rem >> 6, l = rem & 63;
    int n = cb*16 + (l & 15);
    int kbase = kk*32 + (l >> 4)*8;
    ushort4 lo, hi;
    if (n < 100) {
      const float* wp = Ww + (size_t)kbase*100 + n;
      lo.x = f2bf(wp[0]);   lo.y = f2bf(wp[100]); lo.z = f2bf(wp[200]); lo.w = f2bf(wp[300]);
      hi.x = f2bf(wp[400]); hi.y = f2bf(wp[500]); hi.z = f2bf(wp[600]); hi.w = f2bf(wp[700]);
    } else {
      lo.x=lo.y=lo.z=lo.w=0; hi.x=hi.y=hi.z=hi.w=0;
    }
    ushort4* dst = (ushort4*)(Bs + (size_t)idx*8);
    dst[0] = lo; dst[1] = hi;
  }
  if (tid < 128) {
    bwL[tid] = (tid < 100) ? bwv[tid] : 0.0f;
    WcL[tid] = (tid < 100) ? Wcv[tid] : 0.0f;
  }
  __syncthreads();

  const int row0 = blockIdx.x*64 + wid*16;
  const float* Arow = H32 + (size_t)(row0 + me)*256;
  f32x4 acc[7] = {};
#pragma unroll
  for (int kk = 0; kk < 8; ++kk) {
    const float* ap = Arow + kk*32 + quad*8;
    float4 a0 = *(const float4*)(ap);
    float4 a1 = *(const float4*)(ap + 4);
    union { bf16x8 v; unsigned u[4]; } ua;
    ua.u[0] = pack_bf16x2(a0.x, a0.y);
    ua.u[1] = pack_bf16x2(a0.z, a0.w);
    ua.u[2] = pack_bf16x2(a1.x, a1.y);
    ua.u[3] = pack_bf16x2(a1.z, a1.w);
#pragma unroll
    for (int cb = 0; cb < 7; ++cb) {
      bf16x8 bf = *(const bf16x8*)(Bs + ((size_t)(kk*7 + cb)*64 + lane)*8);
      acc[cb] = __builtin_amdgcn_mfma_f32_16x16x32_bf16(ua.v, bf, acc[cb], 0, 0, 0);
    }
  }
#pragma unroll
  for (int r = 0; r < 4; ++r) {
    float contrib = 0.0f;
#pragma unroll
    for (int cb = 0; cb < 7; ++cb) {
      int col = cb*16 + me;
      contrib += tanh_fast(acc[cb][r] + bwL[col]) * WcL[col];
    }
    contrib += __shfl_xor(contrib, 1);
    contrib += __shfl_xor(contrib, 2);
    contrib += __shfl_xor(contrib, 4);
    contrib += __shfl_xor(contrib, 8);
    if (me == 0) svals[row0 + quad*4 + r] = contrib;
  }
}

__global__ void k_combine(const float* __restrict__ svals, const float* __restrict__ H32,
                          float* __restrict__ out)
{
  int tid = blockIdx.x*256 + threadIdx.x;
  int fq = tid & 63, bn = tid >> 6;
  float s0 = svals[bn*3], s1 = svals[bn*3+1], s2 = svals[bn*3+2];
  float mm = fmaxf(s0, fmaxf(s1, s2));
  float e0 = fexp2((s0-mm)*L2E), e1 = fexp2((s1-mm)*L2E), e2 = fexp2((s2-mm)*L2E);
  float inv = frcp(e0 + e1 + e2);
  const f32x4* h0 = (const f32x4*)(H32 + (size_t)bn*768) + fq;
  const f32x4* h1 = (const f32x4*)(H32 + (size_t)bn*768 + 256) + fq;
  const f32x4* h2 = (const f32x4*)(H32 + (size_t)bn*768 + 512) + fq;
  f32x4 r = (e0*(*h0) + e1*(*h1) + e2*(*h2))*inv;
  *((f32x4*)out + (size_t)bn*64 + fq) = r;
}

// ---------------- launcher ----------------

extern "C" void kernel_launch(void* const* d_in, const int* in_sizes, int n_in,
                              void* d_out, int out_size, void* d_ws, size_t ws_size,
                              hipStream_t stream) {
  const float* adj = (const float*)d_in[0];
  const float* X   = (const float*)d_in[1];
  const float* W   = (const float*)d_in[2];
  const float* a1  = (const float*)d_in[3];
  const float* a2  = (const float*)d_in[4];
  const float* Ww  = (const float*)d_in[5];
  const float* bw  = (const float*)d_in[6];
  const float* Wc  = (const float*)d_in[7];
  float* out = (float*)d_out;
  char* ws = (char*)d_ws;

  unsigned short* Xs  = (unsigned short*)(ws + 0);
  unsigned short* Wb  = (unsigned short*)(ws + 16777216);
  float* H32          = (float*)(ws + 0);                // reuses Xs/Wb region
  unsigned short* hsw = (unsigned short*)(ws + 50331648);
  u64* mbA            = (u64*)(ws + 125829120);
  float* rowA         = (float*)(ws + 125829120);        // mbA lvl0, dead after boolmm-1
  float* rowB         = (float*)(ws + 126418944);
  float* rowZ2        = (float*)(ws + 127008768);
  u64* mbT            = (u64*)(ws + 138412032);
  float* fbuf         = (float*)(ws + 157286400);
  float* svals        = (float*)(ws + 159645696);

  k_build_wb<<<608, 256, 0, stream>>>(W, a1, a2, Wb);
  k_xconv<<<4096, 256, 0, stream>>>(X, Xs);
  k_bitpack<<<196608, 256, 0, stream>>>(adj, mbA, mbT);
  k_boolmm<<<3072, 256, 0, stream>>>(mbA, mbA, mbA + 786432, mbT, 3);
  k_boolmm<<<3072, 256, 0, stream>>>(mbA + 786432, mbA, (u64*)nullptr, mbT, 6);
  k_gemm_h<<<2432, 256, 0, stream>>>(Xs, Wb, hsw, fbuf);
  k_rowstats<<<36864, 256, 0, stream>>>(mbT, fbuf, rowA, rowB, rowZ2);
  k_attgemm<<<768, 256, 0, stream>>>(hsw, fbuf, rowA, rowB, rowZ2, mbT, H32);
  k_score<<<768, 256, 0, stream>>>(H32, Ww, bw, Wc, svals);
  k_combine<<<4096, 256, 0, stream>>>(svals, H32, out);
}